// Round 5
// baseline (156.957 us; speedup 1.0000x reference)
//
#include <hip/hip_runtime.h>
#include <hip/hip_bf16.h>
#include <math.h>

#define BB 16
#define NN 256
#define DD 64
#define KTOP 128

typedef short s16x8 __attribute__((ext_vector_type(8)));
typedef float f32x4 __attribute__((ext_vector_type(4)));

typedef union { s16x8 v; unsigned u[4]; } frag_u;
typedef union { __hip_bfloat162 b2; unsigned u; } cvu;

__device__ __forceinline__ float asf(unsigned u){ union{unsigned u;float f;}c; c.u=u; return c.f; }

// split pair of fp32 into bf16 hi (RNE) + bf16 lo (residual, RNE)
__device__ __forceinline__ void split2(float v0, float v1, unsigned& hu, unsigned& lu) {
    cvu c; c.b2 = __float22bfloat162_rn(make_float2(v0, v1));
    unsigned h = c.u;
    float l0 = v0 - asf(h << 16);
    float l1 = v1 - asf(h & 0xffff0000u);
    c.b2 = __float22bfloat162_rn(make_float2(l0, l1));
    hu = h; lu = c.u;
}

// Fused: logits (split-bf16 MFMA, 3-pass) -> tanh/att_w dot -> softmax -> agg -> h -> score.
// Block = (b, 4 i's); 4 waves, wave w owns j-strip [64w,64w+64) in phase 1 and row
// i=ibase+w in phase 2.  B fragments (x_i .* W, i-dependent, j-independent) are built
// ONCE per ii by wave w for et=w and shared via LDS (they were 4x-redundant before).
// acc held as [4 jt][2 e] with a per-half epilogue to cut AGPRs 64->32 (3 waves/SIMD).
__global__ __launch_bounds__(256, 3) void k_fused(
    const float* __restrict__ x, const float* __restrict__ W_att,
    const float* __restrict__ b_att, const float* __restrict__ att_w,
    const float* __restrict__ Wpwa, const float* __restrict__ bpwa,
    const float* __restrict__ Wpna, const float* __restrict__ bpna,
    const float* __restrict__ bnsc, const float* __restrict__ bnbi,
    const float* __restrict__ poolw, const float* __restrict__ poolb,
    float* __restrict__ hbuf, float* __restrict__ scores)
{
    const int ig = blockIdx.x;     // 0..63 : i-group of 4
    const int b  = blockIdx.y;     // 0..15
    const int tid = threadIdx.x;
    const int w = tid >> 6, lane = tid & 63;
    const int quad = lane >> 4, c16 = lane & 15;
    const int jb = w * 64;
    const int ibase = ig * 4;

    __shared__ s16x8 sB[2][4][2][64]; // [ks][et][h/l][lane] frag store, 16 KB
    __shared__ float sXi[4 * 64];     // the block's 4 x_i rows
    __shared__ float sL[4][256];      // logit rows
    __shared__ float sAgg[4][64];

    sXi[tid] = x[(b * NN + ibase + (tid >> 6)) * DD + (tid & 63)];

    const float L2E2 = 2.8853900817779268f;  // 2*log2(e)
    float bawL[4], aww[4];
    #pragma unroll
    for (int et = 0; et < 4; ++et) {
        bawL[et] = b_att[et * 16 + c16] * L2E2;
        aww[et]  = att_w[et * 16 + c16];
    }

    // A fragments: A[m=c16][k=quad*8+t] = x[b][jb+jt*16+c16][ks*32+quad*8+t]
    frag_u Ah[4][2], Al[4][2];
    #pragma unroll
    for (int jt = 0; jt < 4; ++jt) {
        #pragma unroll
        for (int ks = 0; ks < 2; ++ks) {
            const float* xr = &x[(b * NN + jb + jt * 16 + c16) * DD + ks * 32 + quad * 8];
            float4 a0 = *(const float4*)xr;
            float4 a1 = *(const float4*)(xr + 4);
            split2(a0.x, a0.y, Ah[jt][ks].u[0], Al[jt][ks].u[0]);
            split2(a0.z, a0.w, Ah[jt][ks].u[1], Al[jt][ks].u[1]);
            split2(a1.x, a1.y, Ah[jt][ks].u[2], Al[jt][ks].u[2]);
            split2(a1.z, a1.w, Ah[jt][ks].u[3], Al[jt][ks].u[3]);
        }
    }
    __syncthreads();   // sXi ready

    for (int ii = 0; ii < 4; ++ii) {
        // ---- build phase: wave w builds B frags for et=w, ks=0,1 ----
        #pragma unroll
        for (int ks = 0; ks < 2; ++ks) {
            const float* xr = &sXi[ii * 64 + ks * 32 + quad * 8];
            float4 c0 = *(const float4*)xr;
            float4 c1 = *(const float4*)(xr + 4);
            float xiv[8] = {c0.x,c0.y,c0.z,c0.w,c1.x,c1.y,c1.z,c1.w};
            // W direct from global (L2-hot): W_att[(ks*32+quad*8+t)*64 + w*16+c16]
            const float* wp = &W_att[(ks * 32 + quad * 8) * 64 + w * 16 + c16];
            float wv[8];
            #pragma unroll
            for (int t = 0; t < 8; ++t) wv[t] = wp[t * 64];
            frag_u bh, bl;
            split2(wv[0] * xiv[0], wv[1] * xiv[1], bh.u[0], bl.u[0]);
            split2(wv[2] * xiv[2], wv[3] * xiv[3], bh.u[1], bl.u[1]);
            split2(wv[4] * xiv[4], wv[5] * xiv[5], bh.u[2], bl.u[2]);
            split2(wv[6] * xiv[6], wv[7] * xiv[7], bh.u[3], bl.u[3]);
            sB[ks][w][0][lane] = bh.v;
            sB[ks][w][1][lane] = bl.v;
        }
        __syncthreads();

        // ---- MFMA + epilogue, et in two halves (acc = 32 AGPR) ----
        float p[4][4];
        #pragma unroll
        for (int jt = 0; jt < 4; ++jt)
            #pragma unroll
            for (int r = 0; r < 4; ++r) p[jt][r] = 0.0f;

        #pragma unroll
        for (int eth = 0; eth < 2; ++eth) {
            f32x4 acc[4][2];
            #pragma unroll
            for (int jt = 0; jt < 4; ++jt)
                #pragma unroll
                for (int e2 = 0; e2 < 2; ++e2)
                    acc[jt][e2] = (f32x4){0.f, 0.f, 0.f, 0.f};

            #pragma unroll
            for (int ks = 0; ks < 2; ++ks) {
                #pragma unroll
                for (int e2 = 0; e2 < 2; ++e2) {
                    const int et = eth * 2 + e2;
                    s16x8 bh = sB[ks][et][0][lane];
                    s16x8 bl = sB[ks][et][1][lane];
                    #pragma unroll
                    for (int jt = 0; jt < 4; ++jt) {
                        acc[jt][e2] = __builtin_amdgcn_mfma_f32_16x16x32_bf16(Ah[jt][ks].v, bh, acc[jt][e2], 0, 0, 0);
                        acc[jt][e2] = __builtin_amdgcn_mfma_f32_16x16x32_bf16(Al[jt][ks].v, bh, acc[jt][e2], 0, 0, 0);
                        acc[jt][e2] = __builtin_amdgcn_mfma_f32_16x16x32_bf16(Ah[jt][ks].v, bl, acc[jt][e2], 0, 0, 0);
                    }
                }
            }

            // epilogue half: p += aww*tanh(acc+baw);  tanh(u)=1-2/(exp2(L2E2*u)+1)
            #pragma unroll
            for (int e2 = 0; e2 < 2; ++e2) {
                const int et = eth * 2 + e2;
                #pragma unroll
                for (int jt = 0; jt < 4; ++jt) {
                    #pragma unroll
                    for (int r = 0; r < 4; ++r) {
                        float arg = fmaf(acc[jt][e2][r], L2E2, bawL[et]);
                        float m = __builtin_amdgcn_exp2f(arg);
                        float th = fmaf(-2.0f, __builtin_amdgcn_rcpf(m + 1.0f), 1.0f);
                        p[jt][r] = fmaf(aww[et], th, p[jt][r]);
                    }
                }
            }
        }

        // reduce over 16 e-lanes (xor 1,2,4,8 stays within quad); C/D row=quad*4+r
        #pragma unroll
        for (int jt = 0; jt < 4; ++jt) {
            #pragma unroll
            for (int r = 0; r < 4; ++r) {
                float s = p[jt][r];
                s += __shfl_xor(s, 1);
                s += __shfl_xor(s, 2);
                s += __shfl_xor(s, 4);
                s += __shfl_xor(s, 8);
                if (c16 == 0) sL[ii][jb + jt * 16 + quad * 4 + r] = s * 0.5f; // 1/TEMP
            }
        }
        __syncthreads();   // sB reusable; at ii=3 also publishes sL for phase 2
    }

    // ---- phase 2: wave w does softmax/agg/h/score for i = ibase + w ----
    {
        const int i = ibase + w;
        float* row = sL[w];
        float lg0 = row[lane], lg1 = row[lane + 64], lg2 = row[lane + 128], lg3 = row[lane + 192];
        float m = fmaxf(fmaxf(lg0, lg1), fmaxf(lg2, lg3));
        #pragma unroll
        for (int off = 32; off; off >>= 1) m = fmaxf(m, __shfl_xor(m, off));
        float e0 = __expf(lg0 - m), e1 = __expf(lg1 - m), e2 = __expf(lg2 - m), e3 = __expf(lg3 - m);
        float ssum = e0 + e1 + e2 + e3;
        #pragma unroll
        for (int off = 32; off; off >>= 1) ssum += __shfl_xor(ssum, off);
        float inv = 1.0f / ssum;
        row[lane] = e0 * inv; row[lane + 64] = e1 * inv;
        row[lane + 128] = e2 * inv; row[lane + 192] = e3 * inv;
        __asm__ volatile("s_waitcnt lgkmcnt(0)" ::: "memory");

        float agg = 0.0f;
        const float4* A4 = (const float4*)row;
        const float* xb = &x[(b * NN) * DD];
        #pragma unroll 8
        for (int jq = 0; jq < 64; ++jq) {
            float4 a = A4[jq];
            int j = jq * 4;
            agg = fmaf(a.x, xb[(j + 0) * DD + lane], agg);
            agg = fmaf(a.y, xb[(j + 1) * DD + lane], agg);
            agg = fmaf(a.z, xb[(j + 2) * DD + lane], agg);
            agg = fmaf(a.w, xb[(j + 3) * DD + lane], agg);
        }
        sAgg[w][lane] = agg;
        __asm__ volatile("s_waitcnt lgkmcnt(0)" ::: "memory");

        double hacc = (double)bpwa[lane] + (double)bpna[lane];
        #pragma unroll 4
        for (int d = 0; d < 64; ++d) {
            hacc += (double)sAgg[w][d] * (double)Wpwa[d * DD + lane]
                  + (double)sXi[w * 64 + d] * (double)Wpna[d * DD + lane];
        }
        const double bnmul = 0.99999500003749968750e0; // 1/sqrt(1+1e-5)
        double hb = hacc * ((double)bnsc[lane] * bnmul) + (double)bnbi[lane];
        float hf = (float)hb;
        const float LAM = 1.0507009873554805f, ALP = 1.6732632423543772f;
        float hs = hf > 0.0f ? LAM * hf : LAM * ALP * (__expf(hf) - 1.0f);
        hbuf[((b * NN) + i) * DD + lane] = hs;

        double z = (double)hs * (double)poolw[lane];
        #pragma unroll
        for (int off = 32; off; off >>= 1) z += __shfl_xor(z, off);
        if (lane == 0) {
            double zz = z + (double)poolb[0];
            scores[b * NN + i] = (float)(1.0 / (1.0 + exp(-zz)));
        }
    }
}

// per-batch rank-selection topk (score desc, tie: lower idx first) + coalesced gather.
__global__ __launch_bounds__(256) void k_topk(
    const float* __restrict__ scores, const float* __restrict__ hbuf,
    float* __restrict__ out)
{
    const int b = blockIdx.x;
    const int t = threadIdx.x;
    __shared__ float ss[256];
    __shared__ int   perm[KTOP];
    ss[t] = scores[b * NN + t];
    __syncthreads();
    const float my = ss[t];
    int rank = 0;
    #pragma unroll 8
    for (int j = 0; j < 256; ++j) {
        float v = ss[j];
        rank += (v > my) || (v == my && j < t);
    }
    if (rank < KTOP) perm[rank] = t;
    __syncthreads();
    #pragma unroll
    for (int m = t; m < KTOP * DD; m += 256) {
        int r = m >> 6, e = m & 63;
        int i = perm[r];
        out[(b * KTOP + r) * DD + e] = hbuf[((b * NN) + i) * DD + e] * ss[i];
    }
}

extern "C" void kernel_launch(void* const* d_in, const int* in_sizes, int n_in,
                              void* d_out, int out_size, void* d_ws, size_t ws_size,
                              hipStream_t stream) {
    const float* x        = (const float*)d_in[0];
    const float* W_att    = (const float*)d_in[1];
    const float* b_att    = (const float*)d_in[2];
    const float* att_w    = (const float*)d_in[3];
    const float* W_pwa    = (const float*)d_in[4];
    const float* b_pwa    = (const float*)d_in[5];
    const float* W_pna    = (const float*)d_in[6];
    const float* b_pna    = (const float*)d_in[7];
    const float* bn_scale = (const float*)d_in[8];
    const float* bn_bias  = (const float*)d_in[9];
    const float* pool_w   = (const float*)d_in[10];
    const float* pool_b   = (const float*)d_in[11];

    float* hbuf    = (float*)d_ws;                 // 16*256*64
    float* scoresW = hbuf + BB * NN * DD;          // 16*256
    float* out     = (float*)d_out;

    k_fused<<<dim3(64, BB), 256, 0, stream>>>(x, W_att, b_att, att_w,
                                              W_pwa, b_pwa, W_pna, b_pna,
                                              bn_scale, bn_bias, pool_w, pool_b,
                                              hbuf, scoresW);
    k_topk<<<dim3(BB), 256, 0, stream>>>(scoresW, hbuf, out);
}

// Round 6
// 138.770 us; speedup vs baseline: 1.1311x; 1.1311x over previous
//
#include <hip/hip_runtime.h>
#include <hip/hip_bf16.h>
#include <math.h>

#define BB 16
#define NN 256
#define DD 64
#define KTOP 128

typedef short s16x8 __attribute__((ext_vector_type(8)));
typedef float f32x4 __attribute__((ext_vector_type(4)));

typedef union { s16x8 v; unsigned u[4]; } frag_u;
typedef union { __hip_bfloat162 b2; unsigned u; } cvu;

__device__ __forceinline__ float asf(unsigned u){ union{unsigned u;float f;}c; c.u=u; return c.f; }

// split pair of fp32 into bf16 hi (RNE) + bf16 lo (residual, RNE)
__device__ __forceinline__ void split2(float v0, float v1, unsigned& hu, unsigned& lu) {
    cvu c; c.b2 = __float22bfloat162_rn(make_float2(v0, v1));
    unsigned h = c.u;
    float l0 = v0 - asf(h << 16);
    float l1 = v1 - asf(h & 0xffff0000u);
    c.b2 = __float22bfloat162_rn(make_float2(l0, l1));
    hu = h; lu = c.u;
}

// Fused: logits (split-bf16 MFMA, 3-pass) -> tanh/att_w dot -> softmax -> agg -> h -> score.
// Block = (b, 4 i's), 512 threads / 8 waves. Wave w owns j-strip [32w,32w+32) in phase 1
// -> A-frags need only 32 VGPRs (jt in {0,1}), acc 16 AGPR per eth-half => ~95 unified
// regs, fits 4 waves/SIMD (2 blocks/CU) WITHOUT spills (round-5 forced cap spilled 18 MB).
// B frags (x_i .* W, j-independent) built once per ii: wave w builds (ks=w>>2, et=w&3),
// shared via LDS. Phase 2 (softmax/agg/h/score) has no barriers -> runs on waves 0-3 only.
__global__ __launch_bounds__(512, 4) void k_fused(
    const float* __restrict__ x, const float* __restrict__ W_att,
    const float* __restrict__ b_att, const float* __restrict__ att_w,
    const float* __restrict__ Wpwa, const float* __restrict__ bpwa,
    const float* __restrict__ Wpna, const float* __restrict__ bpna,
    const float* __restrict__ bnsc, const float* __restrict__ bnbi,
    const float* __restrict__ poolw, const float* __restrict__ poolb,
    float* __restrict__ hbuf, float* __restrict__ scores)
{
    const int ig = blockIdx.x;     // 0..63 : i-group of 4
    const int b  = blockIdx.y;     // 0..15
    const int tid = threadIdx.x;
    const int w = tid >> 6, lane = tid & 63;
    const int quad = lane >> 4, c16 = lane & 15;
    const int jb = w * 32;
    const int ibase = ig * 4;

    __shared__ s16x8 sB[2][4][2][64]; // [ks][et][h/l][lane] frag store, 16 KB
    __shared__ float sXi[4 * 64];     // the block's 4 x_i rows
    __shared__ float sL[4][256];      // logit rows
    __shared__ float sAgg[4][64];

    if (tid < 256) sXi[tid] = x[(b * NN + ibase + (tid >> 6)) * DD + (tid & 63)];

    const float L2E2 = 2.8853900817779268f;  // 2*log2(e)
    float bawL[4], aww[4];
    #pragma unroll
    for (int et = 0; et < 4; ++et) {
        bawL[et] = b_att[et * 16 + c16] * L2E2;
        aww[et]  = att_w[et * 16 + c16];
    }
    // halfS = 0.5 * sum_e att_w[e]  (for tanh = 1 - 2r algebra; folds the 1/TEMP too)
    float halfS;
    {
        float sa = aww[0] + aww[1] + aww[2] + aww[3];
        sa += __shfl_xor(sa, 1); sa += __shfl_xor(sa, 2);
        sa += __shfl_xor(sa, 4); sa += __shfl_xor(sa, 8);
        halfS = 0.5f * sa;
    }

    // A fragments: A[m=c16][k=quad*8+t] = x[b][jb+jt*16+c16][ks*32+quad*8+t]
    frag_u Ah[2][2], Al[2][2];
    #pragma unroll
    for (int jt = 0; jt < 2; ++jt) {
        #pragma unroll
        for (int ks = 0; ks < 2; ++ks) {
            const float* xr = &x[(b * NN + jb + jt * 16 + c16) * DD + ks * 32 + quad * 8];
            float4 a0 = *(const float4*)xr;
            float4 a1 = *(const float4*)(xr + 4);
            split2(a0.x, a0.y, Ah[jt][ks].u[0], Al[jt][ks].u[0]);
            split2(a0.z, a0.w, Ah[jt][ks].u[1], Al[jt][ks].u[1]);
            split2(a1.x, a1.y, Ah[jt][ks].u[2], Al[jt][ks].u[2]);
            split2(a1.z, a1.w, Ah[jt][ks].u[3], Al[jt][ks].u[3]);
        }
    }
    __syncthreads();   // sXi ready

    const int bks = w >> 2, bet = w & 3;   // this wave's B-build task
    for (int ii = 0; ii < 4; ++ii) {
        // ---- build phase: wave w builds sB[bks][bet] for current ii ----
        {
            const float* xr = &sXi[ii * 64 + bks * 32 + quad * 8];
            float4 c0 = *(const float4*)xr;
            float4 c1 = *(const float4*)(xr + 4);
            float xiv[8] = {c0.x,c0.y,c0.z,c0.w,c1.x,c1.y,c1.z,c1.w};
            const float* wp = &W_att[(bks * 32 + quad * 8) * 64 + bet * 16 + c16];
            float wv[8];
            #pragma unroll
            for (int t = 0; t < 8; ++t) wv[t] = wp[t * 64];
            frag_u bh, bl;
            split2(wv[0] * xiv[0], wv[1] * xiv[1], bh.u[0], bl.u[0]);
            split2(wv[2] * xiv[2], wv[3] * xiv[3], bh.u[1], bl.u[1]);
            split2(wv[4] * xiv[4], wv[5] * xiv[5], bh.u[2], bl.u[2]);
            split2(wv[6] * xiv[6], wv[7] * xiv[7], bh.u[3], bl.u[3]);
            sB[bks][bet][0][lane] = bh.v;
            sB[bks][bet][1][lane] = bl.v;
        }
        __syncthreads();

        // ---- MFMA + epilogue, et in two halves (acc = 16 AGPR) ----
        float p[2][4];
        #pragma unroll
        for (int jt = 0; jt < 2; ++jt)
            #pragma unroll
            for (int r = 0; r < 4; ++r) p[jt][r] = 0.0f;

        #pragma unroll
        for (int eth = 0; eth < 2; ++eth) {
            f32x4 acc[2][2];
            #pragma unroll
            for (int jt = 0; jt < 2; ++jt)
                #pragma unroll
                for (int e2 = 0; e2 < 2; ++e2)
                    acc[jt][e2] = (f32x4){0.f, 0.f, 0.f, 0.f};

            #pragma unroll
            for (int ks = 0; ks < 2; ++ks) {
                #pragma unroll
                for (int e2 = 0; e2 < 2; ++e2) {
                    const int et = eth * 2 + e2;
                    s16x8 bh = sB[ks][et][0][lane];
                    s16x8 bl = sB[ks][et][1][lane];
                    #pragma unroll
                    for (int jt = 0; jt < 2; ++jt) {
                        acc[jt][e2] = __builtin_amdgcn_mfma_f32_16x16x32_bf16(Ah[jt][ks].v, bh, acc[jt][e2], 0, 0, 0);
                        acc[jt][e2] = __builtin_amdgcn_mfma_f32_16x16x32_bf16(Al[jt][ks].v, bh, acc[jt][e2], 0, 0, 0);
                        acc[jt][e2] = __builtin_amdgcn_mfma_f32_16x16x32_bf16(Ah[jt][ks].v, bl, acc[jt][e2], 0, 0, 0);
                    }
                }
            }

            // epilogue half: p += aww * r, r = rcp(exp2(arg)+1); tanh = 1-2r folded via halfS
            #pragma unroll
            for (int e2 = 0; e2 < 2; ++e2) {
                const int et = eth * 2 + e2;
                #pragma unroll
                for (int jt = 0; jt < 2; ++jt) {
                    #pragma unroll
                    for (int r = 0; r < 4; ++r) {
                        float arg = fmaf(acc[jt][e2][r], L2E2, bawL[et]);
                        float m = __builtin_amdgcn_exp2f(arg);
                        float rc = __builtin_amdgcn_rcpf(m + 1.0f);
                        p[jt][r] = fmaf(aww[et], rc, p[jt][r]);
                    }
                }
            }
        }

        // reduce over 16 e-lanes; logits*0.5 = halfS - sum(aww*r).  C/D row=quad*4+r
        #pragma unroll
        for (int jt = 0; jt < 2; ++jt) {
            #pragma unroll
            for (int r = 0; r < 4; ++r) {
                float s = p[jt][r];
                s += __shfl_xor(s, 1);
                s += __shfl_xor(s, 2);
                s += __shfl_xor(s, 4);
                s += __shfl_xor(s, 8);
                if (c16 == 0) sL[ii][jb + jt * 16 + quad * 4 + r] = halfS - s;
            }
        }
        __syncthreads();   // sB reusable; at ii=3 also publishes sL for phase 2
    }

    // ---- phase 2: wave w<4 does softmax/agg/h/score for i = ibase + w (no barriers) ----
    if (w < 4) {
        const int i = ibase + w;
        float* row = sL[w];
        float lg0 = row[lane], lg1 = row[lane + 64], lg2 = row[lane + 128], lg3 = row[lane + 192];
        float m = fmaxf(fmaxf(lg0, lg1), fmaxf(lg2, lg3));
        #pragma unroll
        for (int off = 32; off; off >>= 1) m = fmaxf(m, __shfl_xor(m, off));
        float e0 = __expf(lg0 - m), e1 = __expf(lg1 - m), e2 = __expf(lg2 - m), e3 = __expf(lg3 - m);
        float ssum = e0 + e1 + e2 + e3;
        #pragma unroll
        for (int off = 32; off; off >>= 1) ssum += __shfl_xor(ssum, off);
        float inv = 1.0f / ssum;
        row[lane] = e0 * inv; row[lane + 64] = e1 * inv;
        row[lane + 128] = e2 * inv; row[lane + 192] = e3 * inv;
        __asm__ volatile("s_waitcnt lgkmcnt(0)" ::: "memory");

        float agg = 0.0f;
        const float4* A4 = (const float4*)row;
        const float* xb = &x[(b * NN) * DD];
        #pragma unroll 8
        for (int jq = 0; jq < 64; ++jq) {
            float4 a = A4[jq];
            int j = jq * 4;
            agg = fmaf(a.x, xb[(j + 0) * DD + lane], agg);
            agg = fmaf(a.y, xb[(j + 1) * DD + lane], agg);
            agg = fmaf(a.z, xb[(j + 2) * DD + lane], agg);
            agg = fmaf(a.w, xb[(j + 3) * DD + lane], agg);
        }
        sAgg[w][lane] = agg;
        __asm__ volatile("s_waitcnt lgkmcnt(0)" ::: "memory");

        double hacc = (double)bpwa[lane] + (double)bpna[lane];
        #pragma unroll 4
        for (int d = 0; d < 64; ++d) {
            hacc += (double)sAgg[w][d] * (double)Wpwa[d * DD + lane]
                  + (double)sXi[w * 64 + d] * (double)Wpna[d * DD + lane];
        }
        const double bnmul = 0.99999500003749968750e0; // 1/sqrt(1+1e-5)
        double hb = hacc * ((double)bnsc[lane] * bnmul) + (double)bnbi[lane];
        float hf = (float)hb;
        const float LAM = 1.0507009873554805f, ALP = 1.6732632423543772f;
        float hs = hf > 0.0f ? LAM * hf : LAM * ALP * (__expf(hf) - 1.0f);
        hbuf[((b * NN) + i) * DD + lane] = hs;

        double z = (double)hs * (double)poolw[lane];
        #pragma unroll
        for (int off = 32; off; off >>= 1) z += __shfl_xor(z, off);
        if (lane == 0) {
            double zz = z + (double)poolb[0];
            scores[b * NN + i] = (float)(1.0 / (1.0 + exp(-zz)));
        }
    }
}

// per-batch rank-selection topk (score desc, tie: lower idx first) + coalesced gather.
__global__ __launch_bounds__(256) void k_topk(
    const float* __restrict__ scores, const float* __restrict__ hbuf,
    float* __restrict__ out)
{
    const int b = blockIdx.x;
    const int t = threadIdx.x;
    __shared__ float ss[256];
    __shared__ int   perm[KTOP];
    ss[t] = scores[b * NN + t];
    __syncthreads();
    const float my = ss[t];
    int rank = 0;
    #pragma unroll 8
    for (int j = 0; j < 256; ++j) {
        float v = ss[j];
        rank += (v > my) || (v == my && j < t);
    }
    if (rank < KTOP) perm[rank] = t;
    __syncthreads();
    #pragma unroll
    for (int m = t; m < KTOP * DD; m += 256) {
        int r = m >> 6, e = m & 63;
        int i = perm[r];
        out[(b * KTOP + r) * DD + e] = hbuf[((b * NN) + i) * DD + e] * ss[i];
    }
}

extern "C" void kernel_launch(void* const* d_in, const int* in_sizes, int n_in,
                              void* d_out, int out_size, void* d_ws, size_t ws_size,
                              hipStream_t stream) {
    const float* x        = (const float*)d_in[0];
    const float* W_att    = (const float*)d_in[1];
    const float* b_att    = (const float*)d_in[2];
    const float* att_w    = (const float*)d_in[3];
    const float* W_pwa    = (const float*)d_in[4];
    const float* b_pwa    = (const float*)d_in[5];
    const float* W_pna    = (const float*)d_in[6];
    const float* b_pna    = (const float*)d_in[7];
    const float* bn_scale = (const float*)d_in[8];
    const float* bn_bias  = (const float*)d_in[9];
    const float* pool_w   = (const float*)d_in[10];
    const float* pool_b   = (const float*)d_in[11];

    float* hbuf    = (float*)d_ws;                 // 16*256*64
    float* scoresW = hbuf + BB * NN * DD;          // 16*256
    float* out     = (float*)d_out;

    k_fused<<<dim3(64, BB), 512, 0, stream>>>(x, W_att, b_att, att_w,
                                              W_pwa, b_pwa, W_pna, b_pna,
                                              bn_scale, bn_bias, pool_w, pool_b,
                                              hbuf, scoresW);
    k_topk<<<dim3(BB), 256, 0, stream>>>(scoresW, hbuf, out);
}

// Round 7
// 136.416 us; speedup vs baseline: 1.1506x; 1.0173x over previous
//
#include <hip/hip_runtime.h>
#include <hip/hip_bf16.h>
#include <math.h>

#define BB 16
#define NN 256
#define DD 64
#define KTOP 128

typedef short s16x8 __attribute__((ext_vector_type(8)));
typedef float f32x4 __attribute__((ext_vector_type(4)));

typedef union { s16x8 v; unsigned u[4]; } frag_u;
typedef union { __hip_bfloat162 b2; unsigned u; } cvu;

__device__ __forceinline__ float asf(unsigned u){ union{unsigned u;float f;}c; c.u=u; return c.f; }

// split pair of fp32 into bf16 hi (RNE) + bf16 lo (residual, RNE)
__device__ __forceinline__ void split2(float v0, float v1, unsigned& hu, unsigned& lu) {
    cvu c; c.b2 = __float22bfloat162_rn(make_float2(v0, v1));
    unsigned h = c.u;
    float l0 = v0 - asf(h << 16);
    float l1 = v1 - asf(h & 0xffff0000u);
    c.b2 = __float22bfloat162_rn(make_float2(l0, l1));
    hu = h; lu = c.u;
}

// Fused: logits (split-bf16 MFMA, 3-pass) -> tanh/att_w dot -> softmax -> agg -> h -> score.
// Block = (b, 4 i's), 512 threads / 8 waves; wave w owns j-strip [32w,32w+32).
// B frags (x_i .* W) double-buffered in LDS: build(ii+1) sits in the same barrier
// segment as compute(ii), so MFMA latency shadows build VALU; ONE barrier per ii
// (round-6 had two). W_att slice per wave is ii-invariant -> hoisted to registers.
__global__ __launch_bounds__(512, 4) void k_fused(
    const float* __restrict__ x, const float* __restrict__ W_att,
    const float* __restrict__ b_att, const float* __restrict__ att_w,
    const float* __restrict__ Wpwa, const float* __restrict__ bpwa,
    const float* __restrict__ Wpna, const float* __restrict__ bpna,
    const float* __restrict__ bnsc, const float* __restrict__ bnbi,
    const float* __restrict__ poolw, const float* __restrict__ poolb,
    float* __restrict__ hbuf, float* __restrict__ scores)
{
    const int ig = blockIdx.x;     // 0..63 : i-group of 4
    const int b  = blockIdx.y;     // 0..15
    const int tid = threadIdx.x;
    const int w = tid >> 6, lane = tid & 63;
    const int quad = lane >> 4, c16 = lane & 15;
    const int jb = w * 32;
    const int ibase = ig * 4;

    __shared__ s16x8 sB[2][2][4][2][64]; // [buf][ks][et][h/l][lane], 32 KB
    __shared__ float sXi[4 * 64];        // the block's 4 x_i rows
    __shared__ float sL[4][256];         // logit rows
    __shared__ float sAgg[4][64];

    if (tid < 256) sXi[tid] = x[(b * NN + ibase + (tid >> 6)) * DD + (tid & 63)];

    const float L2E2 = 2.8853900817779268f;  // 2*log2(e)
    float bawL[4], aww[4];
    #pragma unroll
    for (int et = 0; et < 4; ++et) {
        bawL[et] = b_att[et * 16 + c16] * L2E2;
        aww[et]  = att_w[et * 16 + c16];
    }
    // halfS = 0.5 * sum_e att_w[e]  (tanh = 1-2r algebra; folds the 1/TEMP)
    float halfS;
    {
        float sa = aww[0] + aww[1] + aww[2] + aww[3];
        sa += __shfl_xor(sa, 1); sa += __shfl_xor(sa, 2);
        sa += __shfl_xor(sa, 4); sa += __shfl_xor(sa, 8);
        halfS = 0.5f * sa;
    }

    const int bks = w >> 2, bet = w & 3;   // this wave's B-build task
    // hoisted, ii-invariant W slice for the build task
    float wv[8];
    {
        const float* wp = &W_att[(bks * 32 + quad * 8) * 64 + bet * 16 + c16];
        #pragma unroll
        for (int t = 0; t < 8; ++t) wv[t] = wp[t * 64];
    }

    // A fragments: A[m=c16][k=quad*8+t] = x[b][jb+jt*16+c16][ks*32+quad*8+t]
    frag_u Ah[2][2], Al[2][2];
    #pragma unroll
    for (int jt = 0; jt < 2; ++jt) {
        #pragma unroll
        for (int ks = 0; ks < 2; ++ks) {
            const float* xr = &x[(b * NN + jb + jt * 16 + c16) * DD + ks * 32 + quad * 8];
            float4 a0 = *(const float4*)xr;
            float4 a1 = *(const float4*)(xr + 4);
            split2(a0.x, a0.y, Ah[jt][ks].u[0], Al[jt][ks].u[0]);
            split2(a0.z, a0.w, Ah[jt][ks].u[1], Al[jt][ks].u[1]);
            split2(a1.x, a1.y, Ah[jt][ks].u[2], Al[jt][ks].u[2]);
            split2(a1.z, a1.w, Ah[jt][ks].u[3], Al[jt][ks].u[3]);
        }
    }
    __syncthreads();   // sXi ready

    // ---- prologue build: ii=0 into buf 0 ----
    {
        const float* xr = &sXi[0 * 64 + bks * 32 + quad * 8];
        float4 c0 = *(const float4*)xr;
        float4 c1 = *(const float4*)(xr + 4);
        float xiv[8] = {c0.x,c0.y,c0.z,c0.w,c1.x,c1.y,c1.z,c1.w};
        frag_u bh, bl;
        split2(wv[0] * xiv[0], wv[1] * xiv[1], bh.u[0], bl.u[0]);
        split2(wv[2] * xiv[2], wv[3] * xiv[3], bh.u[1], bl.u[1]);
        split2(wv[4] * xiv[4], wv[5] * xiv[5], bh.u[2], bl.u[2]);
        split2(wv[6] * xiv[6], wv[7] * xiv[7], bh.u[3], bl.u[3]);
        sB[0][bks][bet][0][lane] = bh.v;
        sB[0][bks][bet][1][lane] = bl.v;
    }

    #pragma unroll
    for (int ii = 0; ii < 4; ++ii) {
        __syncthreads();  // build(ii) visible; compute(ii-1) done -> buf[(ii+1)&1] free

        // ---- build ii+1 into the other buffer (overlaps compute below) ----
        if (ii < 3) {
            const float* xr = &sXi[(ii + 1) * 64 + bks * 32 + quad * 8];
            float4 c0 = *(const float4*)xr;
            float4 c1 = *(const float4*)(xr + 4);
            float xiv[8] = {c0.x,c0.y,c0.z,c0.w,c1.x,c1.y,c1.z,c1.w};
            frag_u bh, bl;
            split2(wv[0] * xiv[0], wv[1] * xiv[1], bh.u[0], bl.u[0]);
            split2(wv[2] * xiv[2], wv[3] * xiv[3], bh.u[1], bl.u[1]);
            split2(wv[4] * xiv[4], wv[5] * xiv[5], bh.u[2], bl.u[2]);
            split2(wv[6] * xiv[6], wv[7] * xiv[7], bh.u[3], bl.u[3]);
            sB[(ii + 1) & 1][bks][bet][0][lane] = bh.v;
            sB[(ii + 1) & 1][bks][bet][1][lane] = bl.v;
        }

        // ---- MFMA + epilogue from buf[ii&1], et in two halves (acc = 16 AGPR) ----
        const int cur = ii & 1;
        float p[2][4];
        #pragma unroll
        for (int jt = 0; jt < 2; ++jt)
            #pragma unroll
            for (int r = 0; r < 4; ++r) p[jt][r] = 0.0f;

        #pragma unroll
        for (int eth = 0; eth < 2; ++eth) {
            f32x4 acc[2][2];
            #pragma unroll
            for (int jt = 0; jt < 2; ++jt)
                #pragma unroll
                for (int e2 = 0; e2 < 2; ++e2)
                    acc[jt][e2] = (f32x4){0.f, 0.f, 0.f, 0.f};

            #pragma unroll
            for (int ks = 0; ks < 2; ++ks) {
                #pragma unroll
                for (int e2 = 0; e2 < 2; ++e2) {
                    const int et = eth * 2 + e2;
                    s16x8 bh = sB[cur][ks][et][0][lane];
                    s16x8 bl = sB[cur][ks][et][1][lane];
                    #pragma unroll
                    for (int jt = 0; jt < 2; ++jt) {
                        acc[jt][e2] = __builtin_amdgcn_mfma_f32_16x16x32_bf16(Ah[jt][ks].v, bh, acc[jt][e2], 0, 0, 0);
                        acc[jt][e2] = __builtin_amdgcn_mfma_f32_16x16x32_bf16(Al[jt][ks].v, bh, acc[jt][e2], 0, 0, 0);
                        acc[jt][e2] = __builtin_amdgcn_mfma_f32_16x16x32_bf16(Ah[jt][ks].v, bl, acc[jt][e2], 0, 0, 0);
                    }
                }
            }

            // epilogue half: p += aww * r, r = rcp(exp2(arg)+1); tanh = 1-2r via halfS
            #pragma unroll
            for (int e2 = 0; e2 < 2; ++e2) {
                const int et = eth * 2 + e2;
                #pragma unroll
                for (int jt = 0; jt < 2; ++jt) {
                    #pragma unroll
                    for (int r = 0; r < 4; ++r) {
                        float arg = fmaf(acc[jt][e2][r], L2E2, bawL[et]);
                        float m = __builtin_amdgcn_exp2f(arg);
                        float rc = __builtin_amdgcn_rcpf(m + 1.0f);
                        p[jt][r] = fmaf(aww[et], rc, p[jt][r]);
                    }
                }
            }
        }

        // reduce over 16 e-lanes; logits*0.5 = halfS - sum(aww*r).  C/D row=quad*4+r
        #pragma unroll
        for (int jt = 0; jt < 2; ++jt) {
            #pragma unroll
            for (int r = 0; r < 4; ++r) {
                float s = p[jt][r];
                s += __shfl_xor(s, 1);
                s += __shfl_xor(s, 2);
                s += __shfl_xor(s, 4);
                s += __shfl_xor(s, 8);
                if (c16 == 0) sL[ii][jb + jt * 16 + quad * 4 + r] = halfS - s;
            }
        }
    }
    __syncthreads();   // sL complete

    // ---- phase 2: wave w<4 does softmax/agg/h/score for i = ibase + w (no barriers) ----
    if (w < 4) {
        const int i = ibase + w;
        float* row = sL[w];
        float lg0 = row[lane], lg1 = row[lane + 64], lg2 = row[lane + 128], lg3 = row[lane + 192];
        float m = fmaxf(fmaxf(lg0, lg1), fmaxf(lg2, lg3));
        #pragma unroll
        for (int off = 32; off; off >>= 1) m = fmaxf(m, __shfl_xor(m, off));
        float e0 = __expf(lg0 - m), e1 = __expf(lg1 - m), e2 = __expf(lg2 - m), e3 = __expf(lg3 - m);
        float ssum = e0 + e1 + e2 + e3;
        #pragma unroll
        for (int off = 32; off; off >>= 1) ssum += __shfl_xor(ssum, off);
        float inv = 1.0f / ssum;
        row[lane] = e0 * inv; row[lane + 64] = e1 * inv;
        row[lane + 128] = e2 * inv; row[lane + 192] = e3 * inv;
        __asm__ volatile("s_waitcnt lgkmcnt(0)" ::: "memory");

        float agg = 0.0f;
        const float4* A4 = (const float4*)row;
        const float* xb = &x[(b * NN) * DD];
        #pragma unroll 8
        for (int jq = 0; jq < 64; ++jq) {
            float4 a = A4[jq];
            int j = jq * 4;
            agg = fmaf(a.x, xb[(j + 0) * DD + lane], agg);
            agg = fmaf(a.y, xb[(j + 1) * DD + lane], agg);
            agg = fmaf(a.z, xb[(j + 2) * DD + lane], agg);
            agg = fmaf(a.w, xb[(j + 3) * DD + lane], agg);
        }
        sAgg[w][lane] = agg;
        __asm__ volatile("s_waitcnt lgkmcnt(0)" ::: "memory");

        double hacc = (double)bpwa[lane] + (double)bpna[lane];
        #pragma unroll 4
        for (int d = 0; d < 64; ++d) {
            hacc += (double)sAgg[w][d] * (double)Wpwa[d * DD + lane]
                  + (double)sXi[w * 64 + d] * (double)Wpna[d * DD + lane];
        }
        const double bnmul = 0.99999500003749968750e0; // 1/sqrt(1+1e-5)
        double hb = hacc * ((double)bnsc[lane] * bnmul) + (double)bnbi[lane];
        float hf = (float)hb;
        const float LAM = 1.0507009873554805f, ALP = 1.6732632423543772f;
        float hs = hf > 0.0f ? LAM * hf : LAM * ALP * (__expf(hf) - 1.0f);
        hbuf[((b * NN) + i) * DD + lane] = hs;

        double z = (double)hs * (double)poolw[lane];
        #pragma unroll
        for (int off = 32; off; off >>= 1) z += __shfl_xor(z, off);
        if (lane == 0) {
            double zz = z + (double)poolb[0];
            scores[b * NN + i] = (float)(1.0 / (1.0 + exp(-zz)));
        }
    }
}

// rank-selection topk, chunked: block (c,b) handles ranks [16c,16c+16) of batch b.
// score desc, tie: lower idx first — matches lax.top_k.
__global__ __launch_bounds__(256) void k_topk(
    const float* __restrict__ scores, const float* __restrict__ hbuf,
    float* __restrict__ out)
{
    const int c = blockIdx.x;   // 0..7
    const int b = blockIdx.y;   // 0..15
    const int t = threadIdx.x;
    __shared__ float ss[256];
    __shared__ int   perm[16];
    ss[t] = scores[b * NN + t];
    __syncthreads();
    const float my = ss[t];
    int rank = 0;
    #pragma unroll 8
    for (int j = 0; j < 256; ++j) {
        float v = ss[j];
        rank += (v > my) || (v == my && j < t);
    }
    if ((rank >> 4) == c) perm[rank & 15] = t;
    __syncthreads();
    #pragma unroll
    for (int m = t; m < 16 * DD; m += 256) {
        int r = m >> 6, e = m & 63;
        int i = perm[r];
        out[(b * KTOP + c * 16 + r) * DD + e] = hbuf[((b * NN) + i) * DD + e] * ss[i];
    }
}

extern "C" void kernel_launch(void* const* d_in, const int* in_sizes, int n_in,
                              void* d_out, int out_size, void* d_ws, size_t ws_size,
                              hipStream_t stream) {
    const float* x        = (const float*)d_in[0];
    const float* W_att    = (const float*)d_in[1];
    const float* b_att    = (const float*)d_in[2];
    const float* att_w    = (const float*)d_in[3];
    const float* W_pwa    = (const float*)d_in[4];
    const float* b_pwa    = (const float*)d_in[5];
    const float* W_pna    = (const float*)d_in[6];
    const float* b_pna    = (const float*)d_in[7];
    const float* bn_scale = (const float*)d_in[8];
    const float* bn_bias  = (const float*)d_in[9];
    const float* pool_w   = (const float*)d_in[10];
    const float* pool_b   = (const float*)d_in[11];

    float* hbuf    = (float*)d_ws;                 // 16*256*64
    float* scoresW = hbuf + BB * NN * DD;          // 16*256
    float* out     = (float*)d_out;

    k_fused<<<dim3(64, BB), 512, 0, stream>>>(x, W_att, b_att, att_w,
                                              W_pwa, b_pwa, W_pna, b_pna,
                                              bn_scale, bn_bias, pool_w, pool_b,
                                              hbuf, scoresW);
    k_topk<<<dim3(8, BB), 256, 0, stream>>>(scoresW, hbuf, out);
}